// Round 1
// baseline (896.800 us; speedup 1.0000x reference)
//
#include <hip/hip_runtime.h>
#include <math.h>

// Problem constants (from reference)
#define NN 50000
#define EE 800000
#define FIN 128
#define HC 128      // HEADS*HID
#define F2 64       // layer-2 out

// ---------------------------------------------------------------------------
// CSR build: histogram -> scan -> scatter
// ---------------------------------------------------------------------------
__global__ __launch_bounds__(256) void k_hist(const int* __restrict__ dst, int* __restrict__ deg) {
    int e = blockIdx.x * 256 + threadIdx.x;
    if (e < EE) atomicAdd(&deg[dst[e]], 1);
}

// single-block scan over NN degrees -> rowptr (inclusive at i+1) and cursor (exclusive)
__global__ __launch_bounds__(1024) void k_scan(const int* __restrict__ deg,
                                               int* __restrict__ rowptr,
                                               int* __restrict__ cursor) {
    __shared__ int wsums[16];
    __shared__ int carry_s;
    const int t = threadIdx.x;
    const int lane = t & 63;
    const int wid = t >> 6;
    if (t == 0) { carry_s = 0; rowptr[0] = 0; }
    __syncthreads();
    for (int base = 0; base < NN; base += 1024) {
        int idx = base + t;
        int v = (idx < NN) ? deg[idx] : 0;
        int x = v;
        #pragma unroll
        for (int off = 1; off < 64; off <<= 1) {
            int y = __shfl_up(x, off);
            if (lane >= off) x += y;
        }
        if (lane == 63) wsums[wid] = x;
        __syncthreads();
        int carry = carry_s;
        int waveoff = 0;
        for (int j = 0; j < wid; ++j) waveoff += wsums[j];
        int incl = x + waveoff + carry;
        if (idx < NN) { rowptr[idx + 1] = incl; cursor[idx] = incl - v; }
        __syncthreads();
        if (t == 1023) carry_s = incl;
        __syncthreads();
    }
}

__global__ __launch_bounds__(256) void k_scatter(const int* __restrict__ src,
                                                 const int* __restrict__ dst,
                                                 int* __restrict__ cursor,
                                                 int* __restrict__ csrc) {
    int e = blockIdx.x * 256 + threadIdx.x;
    if (e < EE) {
        int d = dst[e];
        int pos = atomicAdd(&cursor[d], 1);
        csrc[pos] = src[e];
    }
}

// ---------------------------------------------------------------------------
// Fused multi-weight GEMM: O_w = X @ W_w (+ B_w), w = 0..NW-1.  K fixed = 128.
// Block: 256 threads; tile 64 rows x FOUT cols. Thread (r = t/4, cg = t%4)
// owns CPT = FOUT/4 output columns.
// ---------------------------------------------------------------------------
template <int FOUT, int NW>
__global__ __launch_bounds__(256) void k_gemm(const float* __restrict__ X,
                                              const float* __restrict__ W0, const float* __restrict__ B0,
                                              const float* __restrict__ W1, const float* __restrict__ B1,
                                              const float* __restrict__ W2,
                                              float* __restrict__ O0, float* __restrict__ O1,
                                              float* __restrict__ O2) {
    constexpr int K = 128;
    constexpr int CPT = FOUT / 4;
    constexpr int KS = CPT + 4;           // LDS k-stride (floats), 16B aligned
    constexpr int CGS = 32 * KS + 4;      // LDS cg-stride, breaks bank aliasing
    __shared__ float Xs[64][K + 4];       // row stride 132 floats = 528B (16B aligned)
    __shared__ float Ws[4 * CGS];

    const int t = threadIdx.x;
    const int r = t >> 2;
    const int cg = t & 3;
    const int row0 = blockIdx.x * 64;

    // stage X tile
    for (int i4 = t; i4 < 64 * (K / 4); i4 += 256) {
        int rr = i4 >> 5;
        int k4 = i4 & 31;
        float4 v = make_float4(0.f, 0.f, 0.f, 0.f);
        int row = row0 + rr;
        if (row < NN) v = *(const float4*)(X + (size_t)row * K + k4 * 4);
        *(float4*)&Xs[rr][k4 * 4] = v;
    }

    const float* Wp[3] = {W0, W1, W2};
    const float* Bp[3] = {B0, B1, nullptr};
    float* Op[3] = {O0, O1, O2};

    #pragma unroll
    for (int w = 0; w < NW; ++w) {
        const float* W = Wp[w];
        float acc[CPT];
        #pragma unroll
        for (int j = 0; j < CPT; ++j) acc[j] = 0.f;

        for (int kk = 0; kk < K; kk += 32) {
            __syncthreads();
            for (int i4 = t; i4 < 32 * (FOUT / 4); i4 += 256) {
                int kr = i4 / (FOUT / 4);
                int c = (i4 % (FOUT / 4)) * 4;
                float4 v = *(const float4*)(W + (size_t)(kk + kr) * FOUT + c);
                int cgo = c / CPT;
                int j = c % CPT;
                *(float4*)&Ws[cgo * CGS + kr * KS + j] = v;
            }
            __syncthreads();
            #pragma unroll
            for (int k = 0; k < 32; ++k) {
                float xv = Xs[r][kk + k];
                #pragma unroll
                for (int j4 = 0; j4 < CPT / 4; ++j4) {
                    float4 wv = *(const float4*)&Ws[cg * CGS + k * KS + j4 * 4];
                    acc[j4 * 4 + 0] = fmaf(xv, wv.x, acc[j4 * 4 + 0]);
                    acc[j4 * 4 + 1] = fmaf(xv, wv.y, acc[j4 * 4 + 1]);
                    acc[j4 * 4 + 2] = fmaf(xv, wv.z, acc[j4 * 4 + 2]);
                    acc[j4 * 4 + 3] = fmaf(xv, wv.w, acc[j4 * 4 + 3]);
                }
            }
        }
        int row = row0 + r;
        if (row < NN) {
            const float* B = Bp[w];
            float* O = Op[w];
            #pragma unroll
            for (int j4 = 0; j4 < CPT / 4; ++j4) {
                int c = cg * CPT + j4 * 4;
                float4 o;
                o.x = acc[j4 * 4 + 0] + (B ? B[c + 0] : 0.f);
                o.y = acc[j4 * 4 + 1] + (B ? B[c + 1] : 0.f);
                o.z = acc[j4 * 4 + 2] + (B ? B[c + 2] : 0.f);
                o.w = acc[j4 * 4 + 3] + (B ? B[c + 3] : 0.f);
                *(float4*)(O + (size_t)row * FOUT + c) = o;
            }
        }
    }
}

// ---------------------------------------------------------------------------
// Aggregation: one wave per destination node, online segment-softmax.
// Layers 0/1: F=128, H=4, C=32; lane l owns channels l (heads 0/1) and l+64
// (heads 2/3); 32-lane butterfly per head-group. Epilogue: +res +bias, ELU.
// Layer 2:    F=64, H=1, C=64; 64-lane butterfly; epilogue +bias only.
// ---------------------------------------------------------------------------
template <bool L2>
__global__ __launch_bounds__(256) void k_agg(const float* __restrict__ XL,
                                             const float* __restrict__ XR,
                                             const float* __restrict__ RES,
                                             const float* __restrict__ att,
                                             const float* __restrict__ bias,
                                             const int* __restrict__ rowptr,
                                             const int* __restrict__ csrc,
                                             float* __restrict__ OUT) {
    const int lane = threadIdx.x & 63;
    const int wid = threadIdx.x >> 6;
    const int n = blockIdx.x * 4 + wid;
    if (n >= NN) return;
    const int beg = rowptr[n];
    const int end = rowptr[n + 1];

    if constexpr (!L2) {
        const float xr0 = XR[(size_t)n * 128 + lane];
        const float xr1 = XR[(size_t)n * 128 + 64 + lane];
        const float a0 = att[lane];
        const float a1 = att[64 + lane];
        float m0 = -__builtin_inff(), m1 = -__builtin_inff();
        float d0 = 0.f, d1 = 0.f, s0 = 0.f, s1 = 0.f;
        for (int i = beg; i < end; ++i) {
            int s = csrc[i];
            float v0 = XL[(size_t)s * 128 + lane];
            float v1 = XL[(size_t)s * 128 + 64 + lane];
            float e0 = v0 + xr0; e0 = e0 > 0.f ? e0 : 0.2f * e0;
            float e1 = v1 + xr1; e1 = e1 > 0.f ? e1 : 0.2f * e1;
            float t0 = a0 * e0, t1 = a1 * e1;
            #pragma unroll
            for (int off = 16; off >= 1; off >>= 1) {
                t0 += __shfl_xor(t0, off);
                t1 += __shfl_xor(t1, off);
            }
            float nm0 = fmaxf(m0, t0), nm1 = fmaxf(m1, t1);
            float sc0 = __expf(m0 - nm0), sc1 = __expf(m1 - nm1);
            float p0 = __expf(t0 - nm0), p1 = __expf(t1 - nm1);
            d0 = d0 * sc0 + p0; s0 = s0 * sc0 + p0 * v0; m0 = nm0;
            d1 = d1 * sc1 + p1; s1 = s1 * sc1 + p1 * v1; m1 = nm1;
        }
        float o0 = (d0 > 0.f) ? s0 / d0 : 0.f;
        float o1 = (d1 > 0.f) ? s1 / d1 : 0.f;
        o0 += RES[(size_t)n * 128 + lane] + bias[lane];
        o1 += RES[(size_t)n * 128 + 64 + lane] + bias[64 + lane];
        o0 = o0 > 0.f ? o0 : __expf(o0) - 1.f;   // ELU
        o1 = o1 > 0.f ? o1 : __expf(o1) - 1.f;
        OUT[(size_t)n * 128 + lane] = o0;
        OUT[(size_t)n * 128 + 64 + lane] = o1;
    } else {
        const float xr0 = XR[(size_t)n * 64 + lane];
        const float a0 = att[lane];
        float m0 = -__builtin_inff(), d0 = 0.f, s0 = 0.f;
        for (int i = beg; i < end; ++i) {
            int s = csrc[i];
            float v0 = XL[(size_t)s * 64 + lane];
            float e0 = v0 + xr0; e0 = e0 > 0.f ? e0 : 0.2f * e0;
            float t0 = a0 * e0;
            #pragma unroll
            for (int off = 32; off >= 1; off >>= 1) t0 += __shfl_xor(t0, off);
            float nm0 = fmaxf(m0, t0);
            float sc0 = __expf(m0 - nm0);
            float p0 = __expf(t0 - nm0);
            d0 = d0 * sc0 + p0; s0 = s0 * sc0 + p0 * v0; m0 = nm0;
        }
        float o0 = (d0 > 0.f) ? s0 / d0 : 0.f;
        o0 += bias[lane];
        OUT[(size_t)n * 64 + lane] = o0;
    }
}

// ---------------------------------------------------------------------------
extern "C" void kernel_launch(void* const* d_in, const int* in_sizes, int n_in,
                              void* d_out, int out_size, void* d_ws, size_t ws_size,
                              hipStream_t stream) {
    const float* x    = (const float*)d_in[0];
    const int*   ei   = (const int*)d_in[1];
    const int*   esrc = ei;
    const int*   edst = ei + EE;

    const float* Wl0 = (const float*)d_in[2];
    const float* bl0 = (const float*)d_in[3];
    const float* Wr0 = (const float*)d_in[4];
    const float* br0 = (const float*)d_in[5];
    const float* at0 = (const float*)d_in[6];
    const float* b0  = (const float*)d_in[7];
    const float* rs0 = (const float*)d_in[8];
    const float* Wl1 = (const float*)d_in[9];
    const float* bl1 = (const float*)d_in[10];
    const float* Wr1 = (const float*)d_in[11];
    const float* br1 = (const float*)d_in[12];
    const float* at1 = (const float*)d_in[13];
    const float* b1  = (const float*)d_in[14];
    const float* rs1 = (const float*)d_in[15];
    const float* Wl2 = (const float*)d_in[16];
    const float* bl2 = (const float*)d_in[17];
    const float* Wr2 = (const float*)d_in[18];
    const float* br2 = (const float*)d_in[19];
    const float* at2 = (const float*)d_in[20];
    const float* b2  = (const float*)d_in[21];

    float* out = (float*)d_out;

    // workspace layout
    float* XL  = (float*)d_ws;                 // [NN*128]
    float* XR  = XL + (size_t)NN * 128;        // [NN*128]
    float* RES = XR + (size_t)NN * 128;        // [NN*128]
    float* H   = RES + (size_t)NN * 128;       // [NN*128]
    int* deg    = (int*)(H + (size_t)NN * 128);
    int* rowptr = deg + NN;                    // NN+1
    int* cursor = rowptr + (NN + 1);
    int* csrc   = cursor + NN;                 // EE

    // --- CSR build (graph identical across layers) ---
    hipMemsetAsync(deg, 0, NN * sizeof(int), stream);
    k_hist<<<(EE + 255) / 256, 256, 0, stream>>>(edst, deg);
    k_scan<<<1, 1024, 0, stream>>>(deg, rowptr, cursor);
    k_scatter<<<(EE + 255) / 256, 256, 0, stream>>>(esrc, edst, cursor, csrc);

    const int gemm_grid = (NN + 63) / 64;
    const int agg_grid  = (NN + 3) / 4;

    // --- Layer 0 ---
    k_gemm<128, 3><<<gemm_grid, 256, 0, stream>>>(x, Wl0, bl0, Wr0, br0, rs0, XL, XR, RES);
    k_agg<false><<<agg_grid, 256, 0, stream>>>(XL, XR, RES, at0, b0, rowptr, csrc, H);

    // --- Layer 1 ---
    k_gemm<128, 3><<<gemm_grid, 256, 0, stream>>>(H, Wl1, bl1, Wr1, br1, rs1, XL, XR, RES);
    k_agg<false><<<agg_grid, 256, 0, stream>>>(XL, XR, RES, at1, b1, rowptr, csrc, H);

    // --- Layer 2 (heads=1, C=64, no residual, no ELU) ---
    k_gemm<64, 2><<<gemm_grid, 256, 0, stream>>>(H, Wl2, bl2, Wr2, br2, nullptr, XL, XR, nullptr);
    k_agg<true><<<agg_grid, 256, 0, stream>>>(XL, XR, nullptr, at2, b2, rowptr, csrc, out);
}

// Round 2
// 823.001 us; speedup vs baseline: 1.0897x; 1.0897x over previous
//
#include <hip/hip_runtime.h>
#include <math.h>

// Problem constants (from reference)
#define NN 50000
#define EE 800000

typedef short v8s __attribute__((ext_vector_type(8)));
typedef float v4f __attribute__((ext_vector_type(4)));

__device__ __forceinline__ ushort f2bf(float f) {
    uint u = __float_as_uint(f);
    uint r = (u + 0x7fffu + ((u >> 16) & 1u)) >> 16;
    return (ushort)r;
}
__device__ __forceinline__ float bf2f(ushort h) {
    return __uint_as_float(((uint)h) << 16);
}

// ---------------------------------------------------------------------------
// CSR build: histogram -> scan -> scatter
// ---------------------------------------------------------------------------
__global__ __launch_bounds__(256) void k_hist(const int* __restrict__ dst, int* __restrict__ deg) {
    int e = blockIdx.x * 256 + threadIdx.x;
    if (e < EE) atomicAdd(&deg[dst[e]], 1);
}

__global__ __launch_bounds__(1024) void k_scan(const int* __restrict__ deg,
                                               int* __restrict__ rowptr,
                                               int* __restrict__ cursor) {
    __shared__ int wsums[16];
    __shared__ int carry_s;
    const int t = threadIdx.x;
    const int lane = t & 63;
    const int wid = t >> 6;
    if (t == 0) { carry_s = 0; rowptr[0] = 0; }
    __syncthreads();
    for (int base = 0; base < NN; base += 1024) {
        int idx = base + t;
        int v = (idx < NN) ? deg[idx] : 0;
        int x = v;
        #pragma unroll
        for (int off = 1; off < 64; off <<= 1) {
            int y = __shfl_up(x, off);
            if (lane >= off) x += y;
        }
        if (lane == 63) wsums[wid] = x;
        __syncthreads();
        int carry = carry_s;
        int waveoff = 0;
        for (int j = 0; j < wid; ++j) waveoff += wsums[j];
        int incl = x + waveoff + carry;
        if (idx < NN) { rowptr[idx + 1] = incl; cursor[idx] = incl - v; }
        __syncthreads();
        if (t == 1023) carry_s = incl;
        __syncthreads();
    }
}

__global__ __launch_bounds__(256) void k_scatter(const int* __restrict__ src,
                                                 const int* __restrict__ dst,
                                                 int* __restrict__ cursor,
                                                 int* __restrict__ csrc) {
    int e = blockIdx.x * 256 + threadIdx.x;
    if (e < EE) {
        int d = dst[e];
        int pos = atomicAdd(&cursor[d], 1);
        csrc[pos] = src[e];
    }
}

// ---------------------------------------------------------------------------
// Weight conversion: W [128 x FOUT] fp32 -> transposed bf16 hi/lo [FOUT x 128]
// All 8 weight matrices in one launch (blockIdx.y selects matrix).
// ---------------------------------------------------------------------------
struct WPack {
    const float* W[8];
    ushort* Th[8];
    ushort* Tl[8];
    int fout[8];
};

__global__ __launch_bounds__(256) void k_conv_w(WPack p) {
    int wi = blockIdx.y;
    int fout = p.fout[wi];
    int total = 128 * fout;
    int i = blockIdx.x * 256 + threadIdx.x;
    if (i >= total) return;
    int k = i / fout;
    int n = i - k * fout;
    float f = p.W[wi][i];
    ushort h = f2bf(f);
    float lo = f - bf2f(h);
    p.Th[wi][n * 128 + k] = h;
    p.Tl[wi][n * 128 + k] = f2bf(lo);
}

// X conversion: fp32 [NN x 128] -> bf16 hi/lo (row-major, same layout)
__global__ __launch_bounds__(256) void k_conv_x(const float* __restrict__ X,
                                                ushort* __restrict__ Xh,
                                                ushort* __restrict__ Xl) {
    int i = (blockIdx.x * 256 + threadIdx.x) * 4;
    if (i >= NN * 128) return;
    float4 v = *(const float4*)(X + i);
    ushort4 h, l;
    h.x = f2bf(v.x); l.x = f2bf(v.x - bf2f(h.x));
    h.y = f2bf(v.y); l.y = f2bf(v.y - bf2f(h.y));
    h.z = f2bf(v.z); l.z = f2bf(v.z - bf2f(h.z));
    h.w = f2bf(v.w); l.w = f2bf(v.w - bf2f(h.w));
    *(ushort4*)(Xh + i) = h;
    *(ushort4*)(Xl + i) = l;
}

// ---------------------------------------------------------------------------
// Split-bf16 MFMA GEMM: O_w = X @ W_w (+ B_w) for w = 0..NW-1, K = 128.
// Block = 256 threads = 4 waves; each wave computes a 16-row strip x FOUT.
// A (X rows) kept in registers (hi+lo, 4 k-chunks); B read from transposed
// bf16 weights in global (hot in L1/L2). acc fp32 via mfma_f32_16x16x32_bf16:
//   acc += Al*Bh + Ah*Bl + Ah*Bh   (Al*Bl dropped, ~2^-16 rel)
// ---------------------------------------------------------------------------
template <int FOUT, int NW>
__global__ __launch_bounds__(256) void k_gemm_mfma(
    const ushort* __restrict__ Xh, const ushort* __restrict__ Xl,
    const ushort* __restrict__ T0h, const ushort* __restrict__ T0l, const float* __restrict__ B0,
    const ushort* __restrict__ T1h, const ushort* __restrict__ T1l, const float* __restrict__ B1,
    const ushort* __restrict__ T2h, const ushort* __restrict__ T2l,
    float* __restrict__ O0, float* __restrict__ O1, float* __restrict__ O2)
{
    const int lane = threadIdx.x & 63;
    const int wid  = threadIdx.x >> 6;
    const int m    = lane & 15;
    const int quad = lane >> 4;
    const int row0 = blockIdx.x * 64 + wid * 16;   // strip base
    int arow = row0 + m;
    if (arow > NN - 1) arow = NN - 1;

    // A fragments: A[m=lane&15][k = quad*8 + j], 4 chunks of K=32, hi & lo
    v8s ah[4], al[4];
    #pragma unroll
    for (int c = 0; c < 4; ++c) {
        size_t off = (size_t)arow * 128 + c * 32 + quad * 8;
        ah[c] = *(const v8s*)(Xh + off);
        al[c] = *(const v8s*)(Xl + off);
    }

    const ushort* Th[3] = {T0h, T1h, T2h};
    const ushort* Tl[3] = {T0l, T1l, T2l};
    const float*  Bs[3] = {B0, B1, nullptr};
    float*        Os[3] = {O0, O1, O2};

    #pragma unroll
    for (int w = 0; w < NW; ++w) {
        const ushort* th = Th[w];
        const ushort* tl = Tl[w];
        const float* bias = Bs[w];
        float* O = Os[w];
        #pragma unroll
        for (int t = 0; t < FOUT / 16; ++t) {
            const int col = t * 16 + m;   // B fragment row = output column
            v4f acc = {0.f, 0.f, 0.f, 0.f};
            #pragma unroll
            for (int c = 0; c < 4; ++c) {
                size_t boff = (size_t)col * 128 + c * 32 + quad * 8;
                v8s bh = *(const v8s*)(th + boff);
                v8s bl = *(const v8s*)(tl + boff);
                acc = __builtin_amdgcn_mfma_f32_16x16x32_bf16(al[c], bh, acc, 0, 0, 0);
                acc = __builtin_amdgcn_mfma_f32_16x16x32_bf16(ah[c], bl, acc, 0, 0, 0);
                acc = __builtin_amdgcn_mfma_f32_16x16x32_bf16(ah[c], bh, acc, 0, 0, 0);
            }
            // D layout: col = lane&15, row = quad*4 + j
            float badd = bias ? bias[col] : 0.f;
            #pragma unroll
            for (int j = 0; j < 4; ++j) {
                int r = row0 + quad * 4 + j;
                if (r < NN) O[(size_t)r * FOUT + col] = acc[j] + badd;
            }
        }
    }
}

// ---------------------------------------------------------------------------
// Aggregation: one wave per destination node, online segment-softmax.
// Layers 0/1 (!L2): F=128, H=4, C=32; epilogue +res +bias, ELU, then emit
// bf16 hi/lo for the next layer's MFMA GEMM.
// Layer 2 (L2): F=64, H=1, C=64; epilogue +bias, fp32 out.
// ---------------------------------------------------------------------------
template <bool L2>
__global__ __launch_bounds__(256) void k_agg(const float* __restrict__ XL,
                                             const float* __restrict__ XR,
                                             const float* __restrict__ RES,
                                             const float* __restrict__ att,
                                             const float* __restrict__ bias,
                                             const int* __restrict__ rowptr,
                                             const int* __restrict__ csrc,
                                             float* __restrict__ OUT,
                                             ushort* __restrict__ Hh,
                                             ushort* __restrict__ Hl) {
    const int lane = threadIdx.x & 63;
    const int wid = threadIdx.x >> 6;
    const int n = blockIdx.x * 4 + wid;
    if (n >= NN) return;
    const int beg = rowptr[n];
    const int end = rowptr[n + 1];

    if constexpr (!L2) {
        const float xr0 = XR[(size_t)n * 128 + lane];
        const float xr1 = XR[(size_t)n * 128 + 64 + lane];
        const float a0 = att[lane];
        const float a1 = att[64 + lane];
        float m0 = -__builtin_inff(), m1 = -__builtin_inff();
        float d0 = 0.f, d1 = 0.f, s0 = 0.f, s1 = 0.f;
        for (int i = beg; i < end; ++i) {
            int s = csrc[i];
            float v0 = XL[(size_t)s * 128 + lane];
            float v1 = XL[(size_t)s * 128 + 64 + lane];
            float e0 = v0 + xr0; e0 = e0 > 0.f ? e0 : 0.2f * e0;
            float e1 = v1 + xr1; e1 = e1 > 0.f ? e1 : 0.2f * e1;
            float t0 = a0 * e0, t1 = a1 * e1;
            #pragma unroll
            for (int off = 16; off >= 1; off >>= 1) {
                t0 += __shfl_xor(t0, off);
                t1 += __shfl_xor(t1, off);
            }
            float nm0 = fmaxf(m0, t0), nm1 = fmaxf(m1, t1);
            float sc0 = __expf(m0 - nm0), sc1 = __expf(m1 - nm1);
            float p0 = __expf(t0 - nm0), p1 = __expf(t1 - nm1);
            d0 = d0 * sc0 + p0; s0 = s0 * sc0 + p0 * v0; m0 = nm0;
            d1 = d1 * sc1 + p1; s1 = s1 * sc1 + p1 * v1; m1 = nm1;
        }
        float o0 = (d0 > 0.f) ? s0 / d0 : 0.f;
        float o1 = (d1 > 0.f) ? s1 / d1 : 0.f;
        o0 += RES[(size_t)n * 128 + lane] + bias[lane];
        o1 += RES[(size_t)n * 128 + 64 + lane] + bias[64 + lane];
        o0 = o0 > 0.f ? o0 : __expf(o0) - 1.f;   // ELU
        o1 = o1 > 0.f ? o1 : __expf(o1) - 1.f;
        ushort h0 = f2bf(o0), h1 = f2bf(o1);
        Hh[(size_t)n * 128 + lane] = h0;
        Hl[(size_t)n * 128 + lane] = f2bf(o0 - bf2f(h0));
        Hh[(size_t)n * 128 + 64 + lane] = h1;
        Hl[(size_t)n * 128 + 64 + lane] = f2bf(o1 - bf2f(h1));
    } else {
        const float xr0 = XR[(size_t)n * 64 + lane];
        const float a0 = att[lane];
        float m0 = -__builtin_inff(), d0 = 0.f, s0 = 0.f;
        for (int i = beg; i < end; ++i) {
            int s = csrc[i];
            float v0 = XL[(size_t)s * 64 + lane];
            float e0 = v0 + xr0; e0 = e0 > 0.f ? e0 : 0.2f * e0;
            float t0 = a0 * e0;
            #pragma unroll
            for (int off = 32; off >= 1; off >>= 1) t0 += __shfl_xor(t0, off);
            float nm0 = fmaxf(m0, t0);
            float sc0 = __expf(m0 - nm0);
            float p0 = __expf(t0 - nm0);
            d0 = d0 * sc0 + p0; s0 = s0 * sc0 + p0 * v0; m0 = nm0;
        }
        float o0 = (d0 > 0.f) ? s0 / d0 : 0.f;
        o0 += bias[lane];
        OUT[(size_t)n * 64 + lane] = o0;
    }
}

// ---------------------------------------------------------------------------
extern "C" void kernel_launch(void* const* d_in, const int* in_sizes, int n_in,
                              void* d_out, int out_size, void* d_ws, size_t ws_size,
                              hipStream_t stream) {
    const float* x    = (const float*)d_in[0];
    const int*   ei   = (const int*)d_in[1];
    const int*   esrc = ei;
    const int*   edst = ei + EE;

    const float* Wl0 = (const float*)d_in[2];
    const float* bl0 = (const float*)d_in[3];
    const float* Wr0 = (const float*)d_in[4];
    const float* br0 = (const float*)d_in[5];
    const float* at0 = (const float*)d_in[6];
    const float* b0  = (const float*)d_in[7];
    const float* rs0 = (const float*)d_in[8];
    const float* Wl1 = (const float*)d_in[9];
    const float* bl1 = (const float*)d_in[10];
    const float* Wr1 = (const float*)d_in[11];
    const float* br1 = (const float*)d_in[12];
    const float* at1 = (const float*)d_in[13];
    const float* b1  = (const float*)d_in[14];
    const float* rs1 = (const float*)d_in[15];
    const float* Wl2 = (const float*)d_in[16];
    const float* bl2 = (const float*)d_in[17];
    const float* Wr2 = (const float*)d_in[18];
    const float* br2 = (const float*)d_in[19];
    const float* at2 = (const float*)d_in[20];
    const float* b2  = (const float*)d_in[21];

    float* out = (float*)d_out;

    // --- workspace layout ---
    float* XL  = (float*)d_ws;                 // [NN*128] fp32
    float* XR  = XL + (size_t)NN * 128;
    float* RES = XR + (size_t)NN * 128;
    ushort* Xh = (ushort*)(RES + (size_t)NN * 128);   // [NN*128] bf16-hi
    ushort* Xl_ = Xh + (size_t)NN * 128;              // [NN*128] bf16-lo
    // transposed bf16 weights: 6 matrices of 16384 + 2 of 8192 (hi then lo)
    ushort* Wth = Xl_ + (size_t)NN * 128;
    const int wsz[8] = {16384, 16384, 16384, 16384, 16384, 16384, 8192, 8192};
    ushort* th[8]; ushort* tl[8];
    {
        ushort* p = Wth;
        for (int i = 0; i < 8; ++i) { th[i] = p; p += wsz[i]; }
        for (int i = 0; i < 8; ++i) { tl[i] = p; p += wsz[i]; }
    }
    int* deg    = (int*)(Wth + 2 * (6 * 16384 + 2 * 8192));
    int* rowptr = deg + NN;                    // NN+1
    int* cursor = rowptr + (NN + 1);
    int* csrc   = cursor + NN;                 // EE

    // --- CSR build (graph identical across layers) ---
    hipMemsetAsync(deg, 0, NN * sizeof(int), stream);
    k_hist<<<(EE + 255) / 256, 256, 0, stream>>>(edst, deg);
    k_scan<<<1, 1024, 0, stream>>>(deg, rowptr, cursor);
    k_scatter<<<(EE + 255) / 256, 256, 0, stream>>>(esrc, edst, cursor, csrc);

    // --- weight + input conversion ---
    WPack wp;
    const float* Ws[8] = {Wl0, Wr0, rs0, Wl1, Wr1, rs1, Wl2, Wr2};
    const int fouts[8] = {128, 128, 128, 128, 128, 128, 64, 64};
    for (int i = 0; i < 8; ++i) { wp.W[i] = Ws[i]; wp.Th[i] = th[i]; wp.Tl[i] = tl[i]; wp.fout[i] = fouts[i]; }
    k_conv_w<<<dim3(64, 8), 256, 0, stream>>>(wp);
    k_conv_x<<<(NN * 128 / 4 + 255) / 256, 256, 0, stream>>>(x, Xh, Xl_);

    const int gemm_grid = (NN + 63) / 64;
    const int agg_grid  = (NN + 3) / 4;

    // --- Layer 0 ---
    k_gemm_mfma<128, 3><<<gemm_grid, 256, 0, stream>>>(Xh, Xl_,
        th[0], tl[0], bl0, th[1], tl[1], br0, th[2], tl[2], XL, XR, RES);
    k_agg<false><<<agg_grid, 256, 0, stream>>>(XL, XR, RES, at0, b0, rowptr, csrc, nullptr, Xh, Xl_);

    // --- Layer 1 ---
    k_gemm_mfma<128, 3><<<gemm_grid, 256, 0, stream>>>(Xh, Xl_,
        th[3], tl[3], bl1, th[4], tl[4], br1, th[5], tl[5], XL, XR, RES);
    k_agg<false><<<agg_grid, 256, 0, stream>>>(XL, XR, RES, at1, b1, rowptr, csrc, nullptr, Xh, Xl_);

    // --- Layer 2 (heads=1, C=64, no residual, no ELU) ---
    k_gemm_mfma<64, 2><<<gemm_grid, 256, 0, stream>>>(Xh, Xl_,
        th[6], tl[6], bl2, th[7], tl[7], br2, nullptr, nullptr, XL, XR, nullptr);
    k_agg<true><<<agg_grid, 256, 0, stream>>>(XL, XR, nullptr, at2, b2, rowptr, csrc, out, nullptr, nullptr);
}

// Round 3
// 593.262 us; speedup vs baseline: 1.5116x; 1.3872x over previous
//
#include <hip/hip_runtime.h>
#include <math.h>

// Problem constants (from reference)
#define NN 50000
#define EE 800000

typedef short v8s __attribute__((ext_vector_type(8)));
typedef float v4f __attribute__((ext_vector_type(4)));

__device__ __forceinline__ ushort f2bf(float f) {
    uint u = __float_as_uint(f);
    uint r = (u + 0x7fffu + ((u >> 16) & 1u)) >> 16;
    return (ushort)r;
}
__device__ __forceinline__ float bf2f(ushort h) {
    return __uint_as_float(((uint)h) << 16);
}
__device__ __forceinline__ float lrelu(float x) {
    return fmaxf(x, 0.f) + 0.2f * fminf(x, 0.f);
}

// DPP-based reductions: xor1/xor2 via quad_perm, cross-quad via row_ror,
// cross-16 via ds_swizzle xor16. All-lane result within each 32-group.
template <int CTRL>
__device__ __forceinline__ float dppadd(float x) {
    int y = __builtin_amdgcn_update_dpp(0, __float_as_int(x), CTRL, 0xf, 0xf, true);
    return x + __int_as_float(y);
}
__device__ __forceinline__ float sum32(float x) {
    x = dppadd<0xB1>(x);    // quad_perm [1,0,3,2]  : xor 1
    x = dppadd<0x4E>(x);    // quad_perm [2,3,0,1]  : xor 2
    x = dppadd<0x124>(x);   // row_ror:4            : cross-quad
    x = dppadd<0x128>(x);   // row_ror:8            : cross-quad
    int y = __builtin_amdgcn_ds_swizzle(__float_as_int(x), 0x401F); // xor 16
    return x + __int_as_float(y);
}
__device__ __forceinline__ float sum64(float x) {
    x = sum32(x);
    return x + __shfl_xor(x, 32);
}
__device__ __forceinline__ float expclamp(float t) {
    return __expf(fminf(fmaxf(t, -60.f), 80.f));
}

// ---------------------------------------------------------------------------
// CSR build: histogram -> scan -> scatter
// ---------------------------------------------------------------------------
__global__ __launch_bounds__(256) void k_hist(const int* __restrict__ dst, int* __restrict__ deg) {
    int e = blockIdx.x * 256 + threadIdx.x;
    if (e < EE) atomicAdd(&deg[dst[e]], 1);
}

__global__ __launch_bounds__(1024) void k_scan(const int* __restrict__ deg,
                                               int* __restrict__ rowptr,
                                               int* __restrict__ cursor) {
    __shared__ int wsums[16];
    __shared__ int carry_s;
    const int t = threadIdx.x;
    const int lane = t & 63;
    const int wid = t >> 6;
    if (t == 0) { carry_s = 0; rowptr[0] = 0; }
    __syncthreads();
    for (int base = 0; base < NN; base += 1024) {
        int idx = base + t;
        int v = (idx < NN) ? deg[idx] : 0;
        int x = v;
        #pragma unroll
        for (int off = 1; off < 64; off <<= 1) {
            int y = __shfl_up(x, off);
            if (lane >= off) x += y;
        }
        if (lane == 63) wsums[wid] = x;
        __syncthreads();
        int carry = carry_s;
        int waveoff = 0;
        for (int j = 0; j < wid; ++j) waveoff += wsums[j];
        int incl = x + waveoff + carry;
        if (idx < NN) { rowptr[idx + 1] = incl; cursor[idx] = incl - v; }
        __syncthreads();
        if (t == 1023) carry_s = incl;
        __syncthreads();
    }
}

__global__ __launch_bounds__(256) void k_scatter(const int* __restrict__ src,
                                                 const int* __restrict__ dst,
                                                 int* __restrict__ cursor,
                                                 int* __restrict__ csrc) {
    int e = blockIdx.x * 256 + threadIdx.x;
    if (e < EE) {
        int d = dst[e];
        int pos = atomicAdd(&cursor[d], 1);
        csrc[pos] = src[e];
    }
}

// ---------------------------------------------------------------------------
// Weight conversion: W [128 x FOUT] fp32 -> bf16 hi/lo in MFMA-fragment order:
// element (col = t*16+m, k = c*32+quad*8+j) at (((t*4+c)*4+quad)*16+m)*8+j.
// GEMM B-loads become contiguous 1KB per (t,c) per wave.
// ---------------------------------------------------------------------------
struct WPack {
    const float* W[8];
    ushort* Th[8];
    ushort* Tl[8];
    int fout[8];
};

__global__ __launch_bounds__(256) void k_conv_w(WPack p) {
    int wi = blockIdx.y;
    int fout = p.fout[wi];
    int total = 128 * fout;
    int i = blockIdx.x * 256 + threadIdx.x;
    if (i >= total) return;
    int k = i / fout;
    int n = i - k * fout;
    float f = p.W[wi][i];
    ushort h = f2bf(f);
    float lo = f - bf2f(h);
    int t = n >> 4, m = n & 15, c = k >> 5, quad = (k >> 3) & 3, j = k & 7;
    int flat = ((((t * 4 + c) * 4 + quad) * 16 + m) << 3) + j;
    p.Th[wi][flat] = h;
    p.Tl[wi][flat] = f2bf(lo);
}

// X conversion: fp32 [NN x 128] -> bf16 hi/lo (row-major)
__global__ __launch_bounds__(256) void k_conv_x(const float* __restrict__ X,
                                                ushort* __restrict__ Xh,
                                                ushort* __restrict__ Xl) {
    int i = (blockIdx.x * 256 + threadIdx.x) * 4;
    if (i >= NN * 128) return;
    float4 v = *(const float4*)(X + i);
    ushort4 h, l;
    h.x = f2bf(v.x); l.x = f2bf(v.x - bf2f(h.x));
    h.y = f2bf(v.y); l.y = f2bf(v.y - bf2f(h.y));
    h.z = f2bf(v.z); l.z = f2bf(v.z - bf2f(h.z));
    h.w = f2bf(v.w); l.w = f2bf(v.w - bf2f(h.w));
    *(ushort4*)(Xh + i) = h;
    *(ushort4*)(Xl + i) = l;
}

// ---------------------------------------------------------------------------
// Split-bf16 MFMA GEMM: O_w = X @ W_w (+ B_w), K=128. 4 waves/block, each
// wave computes a 32-row (2x16 strip) x FOUT slab; B fragments read coalesced
// from fragment-packed weights (L1/L2-hot), reused across both strips.
// If ILV, output channel col is stored at (col&63)*2+(col>>6) (float2-pair
// interleave for the aggregation kernel's single-load gather).
// ---------------------------------------------------------------------------
template <int FOUT, int NW, bool ILV>
__global__ __launch_bounds__(256) void k_gemm_mfma(
    const ushort* __restrict__ Xh, const ushort* __restrict__ Xl,
    const ushort* __restrict__ T0h, const ushort* __restrict__ T0l, const float* __restrict__ B0,
    const ushort* __restrict__ T1h, const ushort* __restrict__ T1l, const float* __restrict__ B1,
    const ushort* __restrict__ T2h, const ushort* __restrict__ T2l,
    float* __restrict__ O0, float* __restrict__ O1, float* __restrict__ O2)
{
    const int lane = threadIdx.x & 63;
    const int wid  = threadIdx.x >> 6;
    const int m    = lane & 15;
    const int quad = lane >> 4;
    const int row0 = blockIdx.x * 128 + wid * 32;

    v8s ah[2][4], al[2][4];
    #pragma unroll
    for (int s = 0; s < 2; ++s) {
        int arow = row0 + s * 16 + m;
        if (arow > NN - 1) arow = NN - 1;
        #pragma unroll
        for (int c = 0; c < 4; ++c) {
            size_t off = (size_t)arow * 128 + c * 32 + quad * 8;
            ah[s][c] = *(const v8s*)(Xh + off);
            al[s][c] = *(const v8s*)(Xl + off);
        }
    }

    const ushort* Th[3] = {T0h, T1h, T2h};
    const ushort* Tl[3] = {T0l, T1l, T2l};
    const float*  Bs[3] = {B0, B1, nullptr};
    float*        Os[3] = {O0, O1, O2};

    #pragma unroll
    for (int w = 0; w < NW; ++w) {
        const ushort* th = Th[w];
        const ushort* tl = Tl[w];
        const float* bias = Bs[w];
        float* O = Os[w];
        #pragma unroll
        for (int t = 0; t < FOUT / 16; ++t) {
            v4f acc[2] = {{0.f,0.f,0.f,0.f},{0.f,0.f,0.f,0.f}};
            #pragma unroll
            for (int c = 0; c < 4; ++c) {
                int boff = t * 2048 + (c * 4 + quad) * 128 + m * 8;
                v8s bh = *(const v8s*)(th + boff);
                v8s bl = *(const v8s*)(tl + boff);
                acc[0] = __builtin_amdgcn_mfma_f32_16x16x32_bf16(al[0][c], bh, acc[0], 0, 0, 0);
                acc[0] = __builtin_amdgcn_mfma_f32_16x16x32_bf16(ah[0][c], bl, acc[0], 0, 0, 0);
                acc[0] = __builtin_amdgcn_mfma_f32_16x16x32_bf16(ah[0][c], bh, acc[0], 0, 0, 0);
                acc[1] = __builtin_amdgcn_mfma_f32_16x16x32_bf16(al[1][c], bh, acc[1], 0, 0, 0);
                acc[1] = __builtin_amdgcn_mfma_f32_16x16x32_bf16(ah[1][c], bl, acc[1], 0, 0, 0);
                acc[1] = __builtin_amdgcn_mfma_f32_16x16x32_bf16(ah[1][c], bh, acc[1], 0, 0, 0);
            }
            const int col = t * 16 + m;
            const int scol = ILV ? ((col & 63) * 2 + (col >> 6)) : col;
            float badd = bias ? bias[col] : 0.f;
            #pragma unroll
            for (int s = 0; s < 2; ++s) {
                #pragma unroll
                for (int j = 0; j < 4; ++j) {
                    int r = row0 + s * 16 + quad * 4 + j;
                    if (r < NN) O[(size_t)r * FOUT + scol] = acc[s][j] + badd;
                }
            }
        }
    }
}

// ---------------------------------------------------------------------------
// Aggregation, layers 0/1: one wave per node. XL/XR/RES interleaved: lane l's
// float2 = channels (l, l+64) = heads (0/1, 2/3). Plain exp softmax (clamped),
// DPP reductions, unroll-2. Epilogue: +res +bias, ELU, emit bf16 hi/lo.
// ---------------------------------------------------------------------------
__global__ __launch_bounds__(256) void k_agg01(const float2* __restrict__ XLp,
                                               const float2* __restrict__ XRp,
                                               const float2* __restrict__ RESp,
                                               const float* __restrict__ att,
                                               const float* __restrict__ bias,
                                               const int* __restrict__ rowptr,
                                               const int* __restrict__ csrc,
                                               ushort* __restrict__ Hh,
                                               ushort* __restrict__ Hl) {
    const int lane = threadIdx.x & 63;
    const int wid = threadIdx.x >> 6;
    const int n = blockIdx.x * 4 + wid;
    if (n >= NN) return;
    const int beg = rowptr[n];
    const int end = rowptr[n + 1];

    const float2 xr = XRp[(size_t)n * 64 + lane];
    const float a0 = att[lane];
    const float a1 = att[64 + lane];
    float d0 = 0.f, d1 = 0.f, s0 = 0.f, s1 = 0.f;

    int i = beg;
    for (; i + 2 <= end; i += 2) {
        int sa = csrc[i], sb = csrc[i + 1];
        float2 va = XLp[(size_t)sa * 64 + lane];
        float2 vb = XLp[(size_t)sb * 64 + lane];
        float ta0 = sum32(a0 * lrelu(va.x + xr.x));
        float tb0 = sum32(a0 * lrelu(vb.x + xr.x));
        float ta1 = sum32(a1 * lrelu(va.y + xr.y));
        float tb1 = sum32(a1 * lrelu(vb.y + xr.y));
        float pa0 = expclamp(ta0), pb0 = expclamp(tb0);
        float pa1 = expclamp(ta1), pb1 = expclamp(tb1);
        d0 += pa0 + pb0;
        d1 += pa1 + pb1;
        s0 = fmaf(pa0, va.x, fmaf(pb0, vb.x, s0));
        s1 = fmaf(pa1, va.y, fmaf(pb1, vb.y, s1));
    }
    if (i < end) {
        int sa = csrc[i];
        float2 va = XLp[(size_t)sa * 64 + lane];
        float ta0 = sum32(a0 * lrelu(va.x + xr.x));
        float ta1 = sum32(a1 * lrelu(va.y + xr.y));
        float pa0 = expclamp(ta0);
        float pa1 = expclamp(ta1);
        d0 += pa0; d1 += pa1;
        s0 = fmaf(pa0, va.x, s0);
        s1 = fmaf(pa1, va.y, s1);
    }

    float o0 = (d0 > 0.f) ? s0 / d0 : 0.f;
    float o1 = (d1 > 0.f) ? s1 / d1 : 0.f;
    float2 rv = RESp[(size_t)n * 64 + lane];
    o0 += rv.x + bias[lane];
    o1 += rv.y + bias[64 + lane];
    o0 = o0 > 0.f ? o0 : __expf(o0) - 1.f;   // ELU
    o1 = o1 > 0.f ? o1 : __expf(o1) - 1.f;
    ushort h0 = f2bf(o0), h1 = f2bf(o1);
    Hh[(size_t)n * 128 + lane] = h0;
    Hl[(size_t)n * 128 + lane] = f2bf(o0 - bf2f(h0));
    Hh[(size_t)n * 128 + 64 + lane] = h1;
    Hl[(size_t)n * 128 + 64 + lane] = f2bf(o1 - bf2f(h1));
}

// Aggregation, layer 2: F=64, H=1; plain layout; 64-lane reduction.
__global__ __launch_bounds__(256) void k_agg2(const float* __restrict__ XL,
                                              const float* __restrict__ XR,
                                              const float* __restrict__ att,
                                              const float* __restrict__ bias,
                                              const int* __restrict__ rowptr,
                                              const int* __restrict__ csrc,
                                              float* __restrict__ OUT) {
    const int lane = threadIdx.x & 63;
    const int wid = threadIdx.x >> 6;
    const int n = blockIdx.x * 4 + wid;
    if (n >= NN) return;
    const int beg = rowptr[n];
    const int end = rowptr[n + 1];

    const float xr0 = XR[(size_t)n * 64 + lane];
    const float a0 = att[lane];
    float d0 = 0.f, s0 = 0.f;

    int i = beg;
    for (; i + 2 <= end; i += 2) {
        int sa = csrc[i], sb = csrc[i + 1];
        float va = XL[(size_t)sa * 64 + lane];
        float vb = XL[(size_t)sb * 64 + lane];
        float ta = sum64(a0 * lrelu(va + xr0));
        float tb = sum64(a0 * lrelu(vb + xr0));
        float pa = expclamp(ta), pb = expclamp(tb);
        d0 += pa + pb;
        s0 = fmaf(pa, va, fmaf(pb, vb, s0));
    }
    if (i < end) {
        int sa = csrc[i];
        float va = XL[(size_t)sa * 64 + lane];
        float ta = sum64(a0 * lrelu(va + xr0));
        float pa = expclamp(ta);
        d0 += pa;
        s0 = fmaf(pa, va, s0);
    }
    float o0 = (d0 > 0.f) ? s0 / d0 : 0.f;
    OUT[(size_t)n * 64 + lane] = o0 + bias[lane];
}

// ---------------------------------------------------------------------------
extern "C" void kernel_launch(void* const* d_in, const int* in_sizes, int n_in,
                              void* d_out, int out_size, void* d_ws, size_t ws_size,
                              hipStream_t stream) {
    const float* x    = (const float*)d_in[0];
    const int*   ei   = (const int*)d_in[1];
    const int*   esrc = ei;
    const int*   edst = ei + EE;

    const float* Wl0 = (const float*)d_in[2];
    const float* bl0 = (const float*)d_in[3];
    const float* Wr0 = (const float*)d_in[4];
    const float* br0 = (const float*)d_in[5];
    const float* at0 = (const float*)d_in[6];
    const float* b0  = (const float*)d_in[7];
    const float* rs0 = (const float*)d_in[8];
    const float* Wl1 = (const float*)d_in[9];
    const float* bl1 = (const float*)d_in[10];
    const float* Wr1 = (const float*)d_in[11];
    const float* br1 = (const float*)d_in[12];
    const float* at1 = (const float*)d_in[13];
    const float* b1  = (const float*)d_in[14];
    const float* rs1 = (const float*)d_in[15];
    const float* Wl2 = (const float*)d_in[16];
    const float* bl2 = (const float*)d_in[17];
    const float* Wr2 = (const float*)d_in[18];
    const float* br2 = (const float*)d_in[19];
    const float* at2 = (const float*)d_in[20];
    const float* b2  = (const float*)d_in[21];

    float* out = (float*)d_out;

    // --- workspace layout ---
    float* XL  = (float*)d_ws;                 // [NN*128] fp32 (interleaved for L0/L1)
    float* XR  = XL + (size_t)NN * 128;
    float* RES = XR + (size_t)NN * 128;
    ushort* Xh = (ushort*)(RES + (size_t)NN * 128);   // [NN*128] bf16-hi
    ushort* Xl_ = Xh + (size_t)NN * 128;              // [NN*128] bf16-lo
    ushort* Wth = Xl_ + (size_t)NN * 128;
    const int wsz[8] = {16384, 16384, 16384, 16384, 16384, 16384, 8192, 8192};
    ushort* th[8]; ushort* tl[8];
    {
        ushort* p = Wth;
        for (int i = 0; i < 8; ++i) { th[i] = p; p += wsz[i]; }
        for (int i = 0; i < 8; ++i) { tl[i] = p; p += wsz[i]; }
    }
    int* deg    = (int*)(Wth + 2 * (6 * 16384 + 2 * 8192));
    int* rowptr = deg + NN;                    // NN+1
    int* cursor = rowptr + (NN + 1);
    int* csrc   = cursor + NN;                 // EE

    // --- CSR build (graph identical across layers) ---
    hipMemsetAsync(deg, 0, NN * sizeof(int), stream);
    k_hist<<<(EE + 255) / 256, 256, 0, stream>>>(edst, deg);
    k_scan<<<1, 1024, 0, stream>>>(deg, rowptr, cursor);
    k_scatter<<<(EE + 255) / 256, 256, 0, stream>>>(esrc, edst, cursor, csrc);

    // --- weight + input conversion ---
    WPack wp;
    const float* Ws[8] = {Wl0, Wr0, rs0, Wl1, Wr1, rs1, Wl2, Wr2};
    const int fouts[8] = {128, 128, 128, 128, 128, 128, 64, 64};
    for (int i = 0; i < 8; ++i) { wp.W[i] = Ws[i]; wp.Th[i] = th[i]; wp.Tl[i] = tl[i]; wp.fout[i] = fouts[i]; }
    k_conv_w<<<dim3(64, 8), 256, 0, stream>>>(wp);
    k_conv_x<<<(NN * 128 / 4 + 255) / 256, 256, 0, stream>>>(x, Xh, Xl_);

    const int gemm_grid = (NN + 127) / 128;
    const int agg_grid  = (NN + 3) / 4;

    // --- Layer 0 ---
    k_gemm_mfma<128, 3, true><<<gemm_grid, 256, 0, stream>>>(Xh, Xl_,
        th[0], tl[0], bl0, th[1], tl[1], br0, th[2], tl[2], XL, XR, RES);
    k_agg01<<<agg_grid, 256, 0, stream>>>((const float2*)XL, (const float2*)XR, (const float2*)RES,
        at0, b0, rowptr, csrc, Xh, Xl_);

    // --- Layer 1 ---
    k_gemm_mfma<128, 3, true><<<gemm_grid, 256, 0, stream>>>(Xh, Xl_,
        th[3], tl[3], bl1, th[4], tl[4], br1, th[5], tl[5], XL, XR, RES);
    k_agg01<<<agg_grid, 256, 0, stream>>>((const float2*)XL, (const float2*)XR, (const float2*)RES,
        at1, b1, rowptr, csrc, Xh, Xl_);

    // --- Layer 2 (heads=1, C=64, no residual, no ELU) ---
    k_gemm_mfma<64, 2, false><<<gemm_grid, 256, 0, stream>>>(Xh, Xl_,
        th[6], tl[6], bl2, th[7], tl[7], br2, nullptr, nullptr, XL, XR, nullptr);
    k_agg2<<<agg_grid, 256, 0, stream>>>(XL, XR, at2, b2, rowptr, csrc, out);
}

// Round 4
// 491.581 us; speedup vs baseline: 1.8243x; 1.2068x over previous
//
#include <hip/hip_runtime.h>
#include <math.h>

// Problem constants (from reference)
#define NN 50000
#define EE 800000
#define NB ((NN + 255) / 256)   // scan blocks

typedef short v8s __attribute__((ext_vector_type(8)));
typedef float v4f __attribute__((ext_vector_type(4)));

__device__ __forceinline__ ushort f2bf(float f) {
    uint u = __float_as_uint(f);
    uint r = (u + 0x7fffu + ((u >> 16) & 1u)) >> 16;
    return (ushort)r;
}
__device__ __forceinline__ float bf2f(ushort h) {
    return __uint_as_float(((uint)h) << 16);
}
// leaky_relu(x,0.2) = 0.6x + 0.4|x|  (2 VALU: mul + fma-with-abs-modifier)
__device__ __forceinline__ float lrelu(float x) {
    return fmaf(0.4f, fabsf(x), 0.6f * x);
}

// DPP partial reductions (no LDS pipe).
template <int CTRL>
__device__ __forceinline__ float dppadd(float x) {
    int y = __builtin_amdgcn_update_dpp(0, __float_as_int(x), CTRL, 0xf, 0xf, true);
    return x + __int_as_float(y);
}
__device__ __forceinline__ float sum8(float x) {   // all-lane sum within 8-groups
    x = dppadd<0xB1>(x);    // quad_perm xor1
    x = dppadd<0x4E>(x);    // quad_perm xor2
    x = dppadd<0x141>(x);   // row_half_mirror (within 8)
    return x;
}
__device__ __forceinline__ float sum16(float x) {  // all-lane sum within 16-rows
    x = sum8(x);
    x = dppadd<0x140>(x);   // row_mirror (within 16)
    return x;
}
__device__ __forceinline__ float expclamp(float t) {
    return __expf(fminf(fmaxf(t, -60.f), 80.f));
}

// ---------------------------------------------------------------------------
// CSR build: histogram -> 3-phase parallel scan -> scatter
// ---------------------------------------------------------------------------
__global__ __launch_bounds__(256) void k_hist(const int* __restrict__ dst, int* __restrict__ deg) {
    int e = blockIdx.x * 256 + threadIdx.x;
    if (e < EE) atomicAdd(&deg[dst[e]], 1);
}

__global__ __launch_bounds__(256) void k_scan1(const int* __restrict__ deg, int* __restrict__ bsum) {
    __shared__ int sm[4];
    int t = threadIdx.x;
    int idx = blockIdx.x * 256 + t;
    int x = (idx < NN) ? deg[idx] : 0;
    #pragma unroll
    for (int o = 1; o < 64; o <<= 1) x += __shfl_xor(x, o);
    if ((t & 63) == 0) sm[t >> 6] = x;
    __syncthreads();
    if (t == 0) bsum[blockIdx.x] = sm[0] + sm[1] + sm[2] + sm[3];
}

__global__ __launch_bounds__(256) void k_scan2(const int* __restrict__ bsum, int* __restrict__ boff) {
    __shared__ int sm[256];
    int t = threadIdx.x;
    int v = (t < NB) ? bsum[t] : 0;
    sm[t] = v;
    __syncthreads();
    for (int o = 1; o < 256; o <<= 1) {
        int a = (t >= o) ? sm[t - o] : 0;
        __syncthreads();
        sm[t] += a;
        __syncthreads();
    }
    if (t < NB) boff[t] = sm[t] - v;   // exclusive
}

__global__ __launch_bounds__(256) void k_scan3(const int* __restrict__ deg,
                                               const int* __restrict__ boff,
                                               int* __restrict__ rowptr,
                                               int* __restrict__ cursor) {
    __shared__ int sm[256];
    int t = threadIdx.x;
    int idx = blockIdx.x * 256 + t;
    int v = (idx < NN) ? deg[idx] : 0;
    sm[t] = v;
    __syncthreads();
    for (int o = 1; o < 256; o <<= 1) {
        int a = (t >= o) ? sm[t - o] : 0;
        __syncthreads();
        sm[t] += a;
        __syncthreads();
    }
    int incl = sm[t] + boff[blockIdx.x];
    if (idx < NN) { rowptr[idx + 1] = incl; cursor[idx] = incl - v; }
    if (idx == 0) rowptr[0] = 0;
}

__global__ __launch_bounds__(256) void k_scatter(const int* __restrict__ src,
                                                 const int* __restrict__ dst,
                                                 int* __restrict__ cursor,
                                                 int* __restrict__ csrc) {
    int e = blockIdx.x * 256 + threadIdx.x;
    if (e < EE) {
        int d = dst[e];
        int pos = atomicAdd(&cursor[d], 1);
        csrc[pos] = src[e];
    }
}

// ---------------------------------------------------------------------------
// Weight conversion: W [128 x FOUT] fp32 -> bf16 hi/lo in MFMA-fragment order:
// element (col = t*16+m, k = c*32+quad*8+j) at (((t*4+c)*4+quad)*16+m)*8+j.
// ---------------------------------------------------------------------------
struct WPack {
    const float* W[8];
    ushort* Th[8];
    ushort* Tl[8];
    int fout[8];
};

__global__ __launch_bounds__(256) void k_conv_w(WPack p) {
    int wi = blockIdx.y;
    int fout = p.fout[wi];
    int total = 128 * fout;
    int i = blockIdx.x * 256 + threadIdx.x;
    if (i >= total) return;
    int k = i / fout;
    int n = i - k * fout;
    float f = p.W[wi][i];
    ushort h = f2bf(f);
    float lo = f - bf2f(h);
    int t = n >> 4, m = n & 15, c = k >> 5, quad = (k >> 3) & 3, j = k & 7;
    int flat = ((((t * 4 + c) * 4 + quad) * 16 + m) << 3) + j;
    p.Th[wi][flat] = h;
    p.Tl[wi][flat] = f2bf(lo);
}

__global__ __launch_bounds__(256) void k_conv_x(const float* __restrict__ X,
                                                ushort* __restrict__ Xh,
                                                ushort* __restrict__ Xl) {
    int i = (blockIdx.x * 256 + threadIdx.x) * 4;
    if (i >= NN * 128) return;
    float4 v = *(const float4*)(X + i);
    ushort4 h, l;
    h.x = f2bf(v.x); l.x = f2bf(v.x - bf2f(h.x));
    h.y = f2bf(v.y); l.y = f2bf(v.y - bf2f(h.y));
    h.z = f2bf(v.z); l.z = f2bf(v.z - bf2f(h.z));
    h.w = f2bf(v.w); l.w = f2bf(v.w - bf2f(h.w));
    *(ushort4*)(Xh + i) = h;
    *(ushort4*)(Xl + i) = l;
}

// ---------------------------------------------------------------------------
// Split-bf16 MFMA GEMM: O_w = X @ W_w (+ B_w), K=128. 4 waves/block, each
// wave computes a 32-row (2x16 strip) x FOUT slab; B fragments read coalesced
// from fragment-packed weights (L1/L2-hot), reused across both strips.
// Output layout: plain row-major (agg kernels now gather float4 directly).
// ---------------------------------------------------------------------------
template <int FOUT, int NW>
__global__ __launch_bounds__(256) void k_gemm_mfma(
    const ushort* __restrict__ Xh, const ushort* __restrict__ Xl,
    const ushort* __restrict__ T0h, const ushort* __restrict__ T0l, const float* __restrict__ B0,
    const ushort* __restrict__ T1h, const ushort* __restrict__ T1l, const float* __restrict__ B1,
    const ushort* __restrict__ T2h, const ushort* __restrict__ T2l,
    float* __restrict__ O0, float* __restrict__ O1, float* __restrict__ O2)
{
    const int lane = threadIdx.x & 63;
    const int wid  = threadIdx.x >> 6;
    const int m    = lane & 15;
    const int quad = lane >> 4;
    const int row0 = blockIdx.x * 128 + wid * 32;

    v8s ah[2][4], al[2][4];
    #pragma unroll
    for (int s = 0; s < 2; ++s) {
        int arow = row0 + s * 16 + m;
        if (arow > NN - 1) arow = NN - 1;
        #pragma unroll
        for (int c = 0; c < 4; ++c) {
            size_t off = (size_t)arow * 128 + c * 32 + quad * 8;
            ah[s][c] = *(const v8s*)(Xh + off);
            al[s][c] = *(const v8s*)(Xl + off);
        }
    }

    const ushort* Th[3] = {T0h, T1h, T2h};
    const ushort* Tl[3] = {T0l, T1l, T2l};
    const float*  Bs[3] = {B0, B1, nullptr};
    float*        Os[3] = {O0, O1, O2};

    #pragma unroll
    for (int w = 0; w < NW; ++w) {
        const ushort* th = Th[w];
        const ushort* tl = Tl[w];
        const float* bias = Bs[w];
        float* O = Os[w];
        #pragma unroll
        for (int t = 0; t < FOUT / 16; ++t) {
            v4f acc[2] = {{0.f,0.f,0.f,0.f},{0.f,0.f,0.f,0.f}};
            #pragma unroll
            for (int c = 0; c < 4; ++c) {
                int boff = t * 2048 + (c * 4 + quad) * 128 + m * 8;
                v8s bh = *(const v8s*)(th + boff);
                v8s bl = *(const v8s*)(tl + boff);
                acc[0] = __builtin_amdgcn_mfma_f32_16x16x32_bf16(al[0][c], bh, acc[0], 0, 0, 0);
                acc[0] = __builtin_amdgcn_mfma_f32_16x16x32_bf16(ah[0][c], bl, acc[0], 0, 0, 0);
                acc[0] = __builtin_amdgcn_mfma_f32_16x16x32_bf16(ah[0][c], bh, acc[0], 0, 0, 0);
                acc[1] = __builtin_amdgcn_mfma_f32_16x16x32_bf16(al[1][c], bh, acc[1], 0, 0, 0);
                acc[1] = __builtin_amdgcn_mfma_f32_16x16x32_bf16(ah[1][c], bl, acc[1], 0, 0, 0);
                acc[1] = __builtin_amdgcn_mfma_f32_16x16x32_bf16(ah[1][c], bh, acc[1], 0, 0, 0);
            }
            const int col = t * 16 + m;
            float badd = bias ? bias[col] : 0.f;
            #pragma unroll
            for (int s = 0; s < 2; ++s) {
                #pragma unroll
                for (int j = 0; j < 4; ++j) {
                    int r = row0 + s * 16 + quad * 4 + j;
                    if (r < NN) O[(size_t)r * FOUT + col] = acc[s][j] + badd;
                }
            }
        }
    }
}

// ---------------------------------------------------------------------------
// Aggregation layers 0/1: one wave per node, TWO edges per wave pass.
// Lane l: half = l>>5 selects edge of the pair; j = l&31 owns channels
// 4j..4j+3 (float4 gather). Head of lane = j>>3 -> logit reduce = sum8 (3 DPP).
// Cross-half combine once per node. Epilogue: +res +bias, ELU, emit bf16 hi/lo.
// ---------------------------------------------------------------------------
__global__ __launch_bounds__(256) void k_agg01(const float4* __restrict__ XL4,
                                               const float4* __restrict__ XR4,
                                               const float4* __restrict__ RES4,
                                               const float* __restrict__ att,
                                               const float* __restrict__ bias,
                                               const int* __restrict__ rowptr,
                                               const int* __restrict__ csrc,
                                               ushort* __restrict__ Hh,
                                               ushort* __restrict__ Hl) {
    const int lane = threadIdx.x & 63;
    const int wid = threadIdx.x >> 6;
    const int n = blockIdx.x * 4 + wid;
    if (n >= NN) return;
    const int beg = rowptr[n];
    const int end = rowptr[n + 1];
    const int half = lane >> 5;
    const int j = lane & 31;

    const float4 xr = XR4[(size_t)n * 32 + j];
    const float4 at = ((const float4*)att)[j];
    float4 s = {0.f, 0.f, 0.f, 0.f};
    float d = 0.f;

    int i = beg;
    // main loop: 4 edges per iteration, 2 independent gathers in flight
    for (; i + 4 <= end; i += 4) {
        int sa = csrc[i + half];
        int sb = csrc[i + 2 + half];
        float4 va = XL4[(size_t)sa * 32 + j];
        float4 vb = XL4[(size_t)sb * 32 + j];
        {
            float t0 = lrelu(va.x + xr.x) * at.x;
            t0 = fmaf(lrelu(va.y + xr.y), at.y, t0);
            t0 = fmaf(lrelu(va.z + xr.z), at.z, t0);
            t0 = fmaf(lrelu(va.w + xr.w), at.w, t0);
            float p = expclamp(sum8(t0));
            d += p;
            s.x = fmaf(p, va.x, s.x); s.y = fmaf(p, va.y, s.y);
            s.z = fmaf(p, va.z, s.z); s.w = fmaf(p, va.w, s.w);
        }
        {
            float t0 = lrelu(vb.x + xr.x) * at.x;
            t0 = fmaf(lrelu(vb.y + xr.y), at.y, t0);
            t0 = fmaf(lrelu(vb.z + xr.z), at.z, t0);
            t0 = fmaf(lrelu(vb.w + xr.w), at.w, t0);
            float p = expclamp(sum8(t0));
            d += p;
            s.x = fmaf(p, vb.x, s.x); s.y = fmaf(p, vb.y, s.y);
            s.z = fmaf(p, vb.z, s.z); s.w = fmaf(p, vb.w, s.w);
        }
    }
    // tail: 1..3 edges
    for (; i < end; i += 2) {
        int ia = i + half;
        if (ia > end - 1) ia = end - 1;
        int sa = csrc[ia];
        float4 va = XL4[(size_t)sa * 32 + j];
        float t0 = lrelu(va.x + xr.x) * at.x;
        t0 = fmaf(lrelu(va.y + xr.y), at.y, t0);
        t0 = fmaf(lrelu(va.z + xr.z), at.z, t0);
        t0 = fmaf(lrelu(va.w + xr.w), at.w, t0);
        float p = expclamp(sum8(t0));
        if (half && (i + 1 >= end)) p = 0.f;
        d += p;
        s.x = fmaf(p, va.x, s.x); s.y = fmaf(p, va.y, s.y);
        s.z = fmaf(p, va.z, s.z); s.w = fmaf(p, va.w, s.w);
    }

    // combine the two edge-halves
    d   += __shfl_xor(d, 32);
    s.x += __shfl_xor(s.x, 32);
    s.y += __shfl_xor(s.y, 32);
    s.z += __shfl_xor(s.z, 32);
    s.w += __shfl_xor(s.w, 32);

    if (half == 0) {
        float inv = (d > 0.f) ? 1.f / d : 0.f;
        float4 rv = RES4[(size_t)n * 32 + j];
        float4 bv = ((const float4*)bias)[j];
        float o0 = fmaf(s.x, inv, rv.x + bv.x);
        float o1 = fmaf(s.y, inv, rv.y + bv.y);
        float o2 = fmaf(s.z, inv, rv.z + bv.z);
        float o3 = fmaf(s.w, inv, rv.w + bv.w);
        o0 = o0 > 0.f ? o0 : __expf(o0) - 1.f;   // ELU
        o1 = o1 > 0.f ? o1 : __expf(o1) - 1.f;
        o2 = o2 > 0.f ? o2 : __expf(o2) - 1.f;
        o3 = o3 > 0.f ? o3 : __expf(o3) - 1.f;
        ushort4 h, l;
        h.x = f2bf(o0); l.x = f2bf(o0 - bf2f(h.x));
        h.y = f2bf(o1); l.y = f2bf(o1 - bf2f(h.y));
        h.z = f2bf(o2); l.z = f2bf(o2 - bf2f(h.z));
        h.w = f2bf(o3); l.w = f2bf(o3 - bf2f(h.w));
        *(ushort4*)(Hh + (size_t)n * 128 + 4 * j) = h;
        *(ushort4*)(Hl + (size_t)n * 128 + 4 * j) = l;
    }
}

// ---------------------------------------------------------------------------
// Aggregation layer 2: F=64, H=1. FOUR edges per wave pass: quarter q = l>>4
// selects edge, jj = l&15 owns channels 4jj..4jj+3. reduce16 = 4 DPP.
// ---------------------------------------------------------------------------
__global__ __launch_bounds__(256) void k_agg2(const float4* __restrict__ XL4,
                                              const float4* __restrict__ XR4,
                                              const float* __restrict__ att,
                                              const float* __restrict__ bias,
                                              const int* __restrict__ rowptr,
                                              const int* __restrict__ csrc,
                                              float* __restrict__ OUT) {
    const int lane = threadIdx.x & 63;
    const int wid = threadIdx.x >> 6;
    const int n = blockIdx.x * 4 + wid;
    if (n >= NN) return;
    const int beg = rowptr[n];
    const int end = rowptr[n + 1];
    const int q = lane >> 4;
    const int jj = lane & 15;

    const float4 xr = XR4[(size_t)n * 16 + jj];
    const float4 at = ((const float4*)att)[jj];
    float4 s = {0.f, 0.f, 0.f, 0.f};
    float d = 0.f;

    for (int i = beg; i < end; i += 4) {
        int ia = i + q;
        if (ia > end - 1) ia = end - 1;
        int sa = csrc[ia];
        float4 v = XL4[(size_t)sa * 16 + jj];
        float t0 = lrelu(v.x + xr.x) * at.x;
        t0 = fmaf(lrelu(v.y + xr.y), at.y, t0);
        t0 = fmaf(lrelu(v.z + xr.z), at.z, t0);
        t0 = fmaf(lrelu(v.w + xr.w), at.w, t0);
        float p = expclamp(sum16(t0));
        if (i + q >= end) p = 0.f;
        d += p;
        s.x = fmaf(p, v.x, s.x); s.y = fmaf(p, v.y, s.y);
        s.z = fmaf(p, v.z, s.z); s.w = fmaf(p, v.w, s.w);
    }

    // combine the four quarters
    d   += __shfl_xor(d, 16);   d   += __shfl_xor(d, 32);
    s.x += __shfl_xor(s.x, 16); s.x += __shfl_xor(s.x, 32);
    s.y += __shfl_xor(s.y, 16); s.y += __shfl_xor(s.y, 32);
    s.z += __shfl_xor(s.z, 16); s.z += __shfl_xor(s.z, 32);
    s.w += __shfl_xor(s.w, 16); s.w += __shfl_xor(s.w, 32);

    if (lane < 16) {
        float inv = (d > 0.f) ? 1.f / d : 0.f;
        float4 bv = ((const float4*)bias)[jj];
        float4 o;
        o.x = fmaf(s.x, inv, bv.x);
        o.y = fmaf(s.y, inv, bv.y);
        o.z = fmaf(s.z, inv, bv.z);
        o.w = fmaf(s.w, inv, bv.w);
        *(float4*)(OUT + (size_t)n * 64 + 4 * jj) = o;
    }
}

// ---------------------------------------------------------------------------
extern "C" void kernel_launch(void* const* d_in, const int* in_sizes, int n_in,
                              void* d_out, int out_size, void* d_ws, size_t ws_size,
                              hipStream_t stream) {
    const float* x    = (const float*)d_in[0];
    const int*   ei   = (const int*)d_in[1];
    const int*   esrc = ei;
    const int*   edst = ei + EE;

    const float* Wl0 = (const float*)d_in[2];
    const float* bl0 = (const float*)d_in[3];
    const float* Wr0 = (const float*)d_in[4];
    const float* br0 = (const float*)d_in[5];
    const float* at0 = (const float*)d_in[6];
    const float* b0  = (const float*)d_in[7];
    const float* rs0 = (const float*)d_in[8];
    const float* Wl1 = (const float*)d_in[9];
    const float* bl1 = (const float*)d_in[10];
    const float* Wr1 = (const float*)d_in[11];
    const float* br1 = (const float*)d_in[12];
    const float* at1 = (const float*)d_in[13];
    const float* b1  = (const float*)d_in[14];
    const float* rs1 = (const float*)d_in[15];
    const float* Wl2 = (const float*)d_in[16];
    const float* bl2 = (const float*)d_in[17];
    const float* Wr2 = (const float*)d_in[18];
    const float* br2 = (const float*)d_in[19];
    const float* at2 = (const float*)d_in[20];
    const float* b2  = (const float*)d_in[21];

    float* out = (float*)d_out;

    // --- workspace layout ---
    float* XL  = (float*)d_ws;                 // [NN*128] fp32 row-major
    float* XR  = XL + (size_t)NN * 128;
    float* RES = XR + (size_t)NN * 128;
    ushort* Xh = (ushort*)(RES + (size_t)NN * 128);   // [NN*128] bf16-hi
    ushort* Xl_ = Xh + (size_t)NN * 128;              // [NN*128] bf16-lo
    ushort* Wth = Xl_ + (size_t)NN * 128;
    const int wsz[8] = {16384, 16384, 16384, 16384, 16384, 16384, 8192, 8192};
    ushort* th[8]; ushort* tl[8];
    {
        ushort* p = Wth;
        for (int i = 0; i < 8; ++i) { th[i] = p; p += wsz[i]; }
        for (int i = 0; i < 8; ++i) { tl[i] = p; p += wsz[i]; }
    }
    int* deg    = (int*)(Wth + 2 * (6 * 16384 + 2 * 8192));
    int* rowptr = deg + NN;                    // NN+1
    int* cursor = rowptr + (NN + 1);
    int* csrc   = cursor + NN;                 // EE
    int* bsum   = csrc + EE;                   // NB
    int* boff   = bsum + NB;                   // NB

    // --- CSR build (graph identical across layers) ---
    hipMemsetAsync(deg, 0, NN * sizeof(int), stream);
    k_hist<<<(EE + 255) / 256, 256, 0, stream>>>(edst, deg);
    k_scan1<<<NB, 256, 0, stream>>>(deg, bsum);
    k_scan2<<<1, 256, 0, stream>>>(bsum, boff);
    k_scan3<<<NB, 256, 0, stream>>>(deg, boff, rowptr, cursor);
    k_scatter<<<(EE + 255) / 256, 256, 0, stream>>>(esrc, edst, cursor, csrc);

    // --- weight + input conversion ---
    WPack wp;
    const float* Ws[8] = {Wl0, Wr0, rs0, Wl1, Wr1, rs1, Wl2, Wr2};
    const int fouts[8] = {128, 128, 128, 128, 128, 128, 64, 64};
    for (int i = 0; i < 8; ++i) { wp.W[i] = Ws[i]; wp.Th[i] = th[i]; wp.Tl[i] = tl[i]; wp.fout[i] = fouts[i]; }
    k_conv_w<<<dim3(64, 8), 256, 0, stream>>>(wp);
    k_conv_x<<<(NN * 128 / 4 + 255) / 256, 256, 0, stream>>>(x, Xh, Xl_);

    const int gemm_grid = (NN + 127) / 128;
    const int agg_grid  = (NN + 3) / 4;

    // --- Layer 0 ---
    k_gemm_mfma<128, 3><<<gemm_grid, 256, 0, stream>>>(Xh, Xl_,
        th[0], tl[0], bl0, th[1], tl[1], br0, th[2], tl[2], XL, XR, RES);
    k_agg01<<<agg_grid, 256, 0, stream>>>((const float4*)XL, (const float4*)XR, (const float4*)RES,
        at0, b0, rowptr, csrc, Xh, Xl_);

    // --- Layer 1 ---
    k_gemm_mfma<128, 3><<<gemm_grid, 256, 0, stream>>>(Xh, Xl_,
        th[3], tl[3], bl1, th[4], tl[4], br1, th[5], tl[5], XL, XR, RES);
    k_agg01<<<agg_grid, 256, 0, stream>>>((const float4*)XL, (const float4*)XR, (const float4*)RES,
        at1, b1, rowptr, csrc, Xh, Xl_);

    // --- Layer 2 (heads=1, C=64, no residual, no ELU) ---
    k_gemm_mfma<64, 2><<<gemm_grid, 256, 0, stream>>>(Xh, Xl_,
        th[6], tl[6], bl2, th[7], tl[7], br2, nullptr, nullptr, XL, XR, nullptr);
    k_agg2<<<agg_grid, 256, 0, stream>>>((const float4*)XL, (const float4*)XR, at2, b2, rowptr, csrc, out);
}

// Round 5
// 476.129 us; speedup vs baseline: 1.8835x; 1.0325x over previous
//
#include <hip/hip_runtime.h>
#include <math.h>

// Problem constants (from reference)
#define NN 50000
#define EE 800000
#define NB ((NN + 255) / 256)   // scan blocks

typedef short v8s __attribute__((ext_vector_type(8)));
typedef float v4f __attribute__((ext_vector_type(4)));

__device__ __forceinline__ ushort f2bf(float f) {
    uint u = __float_as_uint(f);
    uint r = (u + 0x7fffu + ((u >> 16) & 1u)) >> 16;
    return (ushort)r;
}
__device__ __forceinline__ float bf2f(ushort h) {
    return __uint_as_float(((uint)h) << 16);
}
// leaky_relu(x,0.2) = 0.6x + 0.4|x|
__device__ __forceinline__ float lrelu(float x) {
    return fmaf(0.4f, fabsf(x), 0.6f * x);
}

// DPP partial reductions (no LDS pipe).
template <int CTRL>
__device__ __forceinline__ float dppadd(float x) {
    int y = __builtin_amdgcn_update_dpp(0, __float_as_int(x), CTRL, 0xf, 0xf, true);
    return x + __int_as_float(y);
}
__device__ __forceinline__ float sum8(float x) {   // all-lane sum within 8-groups
    x = dppadd<0xB1>(x);    // quad_perm xor1
    x = dppadd<0x4E>(x);    // quad_perm xor2
    x = dppadd<0x141>(x);   // row_half_mirror
    return x;
}
__device__ __forceinline__ float sum16(float x) {  // all-lane sum within 16-rows
    x = sum8(x);
    x = dppadd<0x140>(x);   // row_mirror
    return x;
}
__device__ __forceinline__ float expclamp(float t) {
    return __expf(fminf(fmaxf(t, -60.f), 80.f));
}

// ---------------------------------------------------------------------------
// CSR build: histogram -> 3-phase parallel scan -> scatter
// ---------------------------------------------------------------------------
__global__ __launch_bounds__(256) void k_hist(const int* __restrict__ dst, int* __restrict__ deg) {
    int e = blockIdx.x * 256 + threadIdx.x;
    if (e < EE) atomicAdd(&deg[dst[e]], 1);
}

__global__ __launch_bounds__(256) void k_scan1(const int* __restrict__ deg, int* __restrict__ bsum) {
    __shared__ int sm[4];
    int t = threadIdx.x;
    int idx = blockIdx.x * 256 + t;
    int x = (idx < NN) ? deg[idx] : 0;
    #pragma unroll
    for (int o = 1; o < 64; o <<= 1) x += __shfl_xor(x, o);
    if ((t & 63) == 0) sm[t >> 6] = x;
    __syncthreads();
    if (t == 0) bsum[blockIdx.x] = sm[0] + sm[1] + sm[2] + sm[3];
}

__global__ __launch_bounds__(256) void k_scan2(const int* __restrict__ bsum, int* __restrict__ boff) {
    __shared__ int sm[256];
    int t = threadIdx.x;
    int v = (t < NB) ? bsum[t] : 0;
    sm[t] = v;
    __syncthreads();
    for (int o = 1; o < 256; o <<= 1) {
        int a = (t >= o) ? sm[t - o] : 0;
        __syncthreads();
        sm[t] += a;
        __syncthreads();
    }
    if (t < NB) boff[t] = sm[t] - v;   // exclusive
}

__global__ __launch_bounds__(256) void k_scan3(const int* __restrict__ deg,
                                               const int* __restrict__ boff,
                                               int* __restrict__ rowptr,
                                               int* __restrict__ cursor) {
    __shared__ int sm[256];
    int t = threadIdx.x;
    int idx = blockIdx.x * 256 + t;
    int v = (idx < NN) ? deg[idx] : 0;
    sm[t] = v;
    __syncthreads();
    for (int o = 1; o < 256; o <<= 1) {
        int a = (t >= o) ? sm[t - o] : 0;
        __syncthreads();
        sm[t] += a;
        __syncthreads();
    }
    int incl = sm[t] + boff[blockIdx.x];
    if (idx < NN) { rowptr[idx + 1] = incl; cursor[idx] = incl - v; }
    if (idx == 0) rowptr[0] = 0;
}

__global__ __launch_bounds__(256) void k_scatter(const int* __restrict__ src,
                                                 const int* __restrict__ dst,
                                                 int* __restrict__ cursor,
                                                 int* __restrict__ csrc) {
    int e = blockIdx.x * 256 + threadIdx.x;
    if (e < EE) {
        int d = dst[e];
        int pos = atomicAdd(&cursor[d], 1);
        csrc[pos] = src[e];
    }
}

// ---------------------------------------------------------------------------
// Weight conversion: W [128 x FOUT] fp32 -> bf16 hi/lo in MFMA-fragment order:
// element (col = t*16+m, k = c*32+quad*8+j) at (((t*4+c)*4+quad)*16+m)*8+j.
// ---------------------------------------------------------------------------
struct WPack {
    const float* W[8];
    ushort* Th[8];
    ushort* Tl[8];
    int fout[8];
};

__global__ __launch_bounds__(256) void k_conv_w(WPack p) {
    int wi = blockIdx.y;
    int fout = p.fout[wi];
    int total = 128 * fout;
    int i = blockIdx.x * 256 + threadIdx.x;
    if (i >= total) return;
    int k = i / fout;
    int n = i - k * fout;
    float f = p.W[wi][i];
    ushort h = f2bf(f);
    float lo = f - bf2f(h);
    int t = n >> 4, m = n & 15, c = k >> 5, quad = (k >> 3) & 3, j = k & 7;
    int flat = ((((t * 4 + c) * 4 + quad) * 16 + m) << 3) + j;
    p.Th[wi][flat] = h;
    p.Tl[wi][flat] = f2bf(lo);
}

// ---------------------------------------------------------------------------
// Split-bf16 MFMA GEMM: O_w = X @ W_w (+ B_w), K=128. 4 waves/block, each
// wave computes a 32-row (2x16 strip) x FOUT slab; B fragments read coalesced
// from fragment-packed weights (L1/L2-hot), reused across both strips.
// CVT=true: A read from fp32 X and split to bf16 hi/lo on the fly (layer 0).
// CVT=false: A read from pre-split Xh/Xl (layers 1/2 — agg epilogue emits).
// ---------------------------------------------------------------------------
template <int FOUT, int NW, bool CVT>
__global__ __launch_bounds__(256) void k_gemm_mfma(
    const float* __restrict__ Xf,
    const ushort* __restrict__ Xh, const ushort* __restrict__ Xl,
    const ushort* __restrict__ T0h, const ushort* __restrict__ T0l, const float* __restrict__ B0,
    const ushort* __restrict__ T1h, const ushort* __restrict__ T1l, const float* __restrict__ B1,
    const ushort* __restrict__ T2h, const ushort* __restrict__ T2l,
    float* __restrict__ O0, float* __restrict__ O1, float* __restrict__ O2)
{
    const int lane = threadIdx.x & 63;
    const int wid  = threadIdx.x >> 6;
    const int m    = lane & 15;
    const int quad = lane >> 4;
    const int row0 = blockIdx.x * 128 + wid * 32;

    v8s ah[2][4], al[2][4];
    #pragma unroll
    for (int s = 0; s < 2; ++s) {
        int arow = row0 + s * 16 + m;
        if (arow > NN - 1) arow = NN - 1;
        #pragma unroll
        for (int c = 0; c < 4; ++c) {
            size_t off = (size_t)arow * 128 + c * 32 + quad * 8;
            if constexpr (CVT) {
                float4 f0 = *(const float4*)(Xf + off);
                float4 f1 = *(const float4*)(Xf + off + 4);
                const float fe[8] = {f0.x, f0.y, f0.z, f0.w, f1.x, f1.y, f1.z, f1.w};
                #pragma unroll
                for (int e = 0; e < 8; ++e) {
                    ushort h = f2bf(fe[e]);
                    float lo = fe[e] - bf2f(h);
                    ah[s][c][e] = (short)h;
                    al[s][c][e] = (short)(__float_as_uint(lo) >> 16);  // truncate lo
                }
            } else {
                ah[s][c] = *(const v8s*)(Xh + off);
                al[s][c] = *(const v8s*)(Xl + off);
            }
        }
    }

    const ushort* Th[3] = {T0h, T1h, T2h};
    const ushort* Tl[3] = {T0l, T1l, T2l};
    const float*  Bs[3] = {B0, B1, nullptr};
    float*        Os[3] = {O0, O1, O2};

    #pragma unroll
    for (int w = 0; w < NW; ++w) {
        const ushort* th = Th[w];
        const ushort* tl = Tl[w];
        const float* bias = Bs[w];
        float* O = Os[w];
        #pragma unroll
        for (int t = 0; t < FOUT / 16; ++t) {
            v4f acc[2] = {{0.f,0.f,0.f,0.f},{0.f,0.f,0.f,0.f}};
            #pragma unroll
            for (int c = 0; c < 4; ++c) {
                int boff = t * 2048 + (c * 4 + quad) * 128 + m * 8;
                v8s bh = *(const v8s*)(th + boff);
                v8s bl = *(const v8s*)(tl + boff);
                acc[0] = __builtin_amdgcn_mfma_f32_16x16x32_bf16(al[0][c], bh, acc[0], 0, 0, 0);
                acc[0] = __builtin_amdgcn_mfma_f32_16x16x32_bf16(ah[0][c], bl, acc[0], 0, 0, 0);
                acc[0] = __builtin_amdgcn_mfma_f32_16x16x32_bf16(ah[0][c], bh, acc[0], 0, 0, 0);
                acc[1] = __builtin_amdgcn_mfma_f32_16x16x32_bf16(al[1][c], bh, acc[1], 0, 0, 0);
                acc[1] = __builtin_amdgcn_mfma_f32_16x16x32_bf16(ah[1][c], bl, acc[1], 0, 0, 0);
                acc[1] = __builtin_amdgcn_mfma_f32_16x16x32_bf16(ah[1][c], bh, acc[1], 0, 0, 0);
            }
            const int col = t * 16 + m;
            float badd = bias ? bias[col] : 0.f;
            #pragma unroll
            for (int s = 0; s < 2; ++s) {
                #pragma unroll
                for (int j = 0; j < 4; ++j) {
                    int r = row0 + s * 16 + quad * 4 + j;
                    if (r < NN) O[(size_t)r * FOUT + col] = acc[s][j] + badd;
                }
            }
        }
    }
}

// ---------------------------------------------------------------------------
// Aggregation layers 0/1: one wave per node, 8 edges per main-loop iteration
// (4 masked pair-passes; 4 independent float4 gathers in flight).
// Lane l: half = l>>5 selects edge of each pair; j = l&31 owns channels
// 4j..4j+3. Head = j>>3 -> logit reduce = sum8 (3 DPP). Cross-half combine
// once per node. Epilogue: +res +bias, ELU, emit bf16 hi/lo.
// ---------------------------------------------------------------------------
__global__ __launch_bounds__(256) void k_agg01(const float4* __restrict__ XL4,
                                               const float4* __restrict__ XR4,
                                               const float4* __restrict__ RES4,
                                               const float* __restrict__ att,
                                               const float* __restrict__ bias,
                                               const int* __restrict__ rowptr,
                                               const int* __restrict__ csrc,
                                               ushort* __restrict__ Hh,
                                               ushort* __restrict__ Hl) {
    const int lane = threadIdx.x & 63;
    const int wid = threadIdx.x >> 6;
    const int n = blockIdx.x * 4 + wid;
    if (n >= NN) return;
    const int beg = rowptr[n];
    const int end = rowptr[n + 1];
    const int half = lane >> 5;
    const int j = lane & 31;

    const float4 xr = XR4[(size_t)n * 32 + j];
    const float4 at = ((const float4*)att)[j];
    float4 s = {0.f, 0.f, 0.f, 0.f};
    float d = 0.f;

    for (int i = beg; i < end; i += 8) {
        int i0 = i + half;
        int i1 = i + 2 + half;
        int i2 = i + 4 + half;
        int i3 = i + 6 + half;
        int e1 = end - 1;
        int s0 = csrc[min(i0, e1)];
        int s1 = csrc[min(i1, e1)];
        int s2 = csrc[min(i2, e1)];
        int s3 = csrc[min(i3, e1)];
        float4 v0 = XL4[(size_t)s0 * 32 + j];
        float4 v1 = XL4[(size_t)s1 * 32 + j];
        float4 v2 = XL4[(size_t)s2 * 32 + j];
        float4 v3 = XL4[(size_t)s3 * 32 + j];
        #pragma unroll
        for (int u = 0; u < 4; ++u) {
            float4 v = (u == 0) ? v0 : (u == 1) ? v1 : (u == 2) ? v2 : v3;
            int ii = (u == 0) ? i0 : (u == 1) ? i1 : (u == 2) ? i2 : i3;
            float t0 = lrelu(v.x + xr.x) * at.x;
            t0 = fmaf(lrelu(v.y + xr.y), at.y, t0);
            t0 = fmaf(lrelu(v.z + xr.z), at.z, t0);
            t0 = fmaf(lrelu(v.w + xr.w), at.w, t0);
            float p = expclamp(sum8(t0));
            if (ii >= end) p = 0.f;
            d += p;
            s.x = fmaf(p, v.x, s.x); s.y = fmaf(p, v.y, s.y);
            s.z = fmaf(p, v.z, s.z); s.w = fmaf(p, v.w, s.w);
        }
    }

    // combine the two edge-halves
    d   += __shfl_xor(d, 32);
    s.x += __shfl_xor(s.x, 32);
    s.y += __shfl_xor(s.y, 32);
    s.z += __shfl_xor(s.z, 32);
    s.w += __shfl_xor(s.w, 32);

    if (half == 0) {
        float inv = (d > 0.f) ? 1.f / d : 0.f;
        float4 rv = RES4[(size_t)n * 32 + j];
        float4 bv = ((const float4*)bias)[j];
        float o0 = fmaf(s.x, inv, rv.x + bv.x);
        float o1 = fmaf(s.y, inv, rv.y + bv.y);
        float o2 = fmaf(s.z, inv, rv.z + bv.z);
        float o3 = fmaf(s.w, inv, rv.w + bv.w);
        o0 = o0 > 0.f ? o0 : __expf(o0) - 1.f;   // ELU
        o1 = o1 > 0.f ? o1 : __expf(o1) - 1.f;
        o2 = o2 > 0.f ? o2 : __expf(o2) - 1.f;
        o3 = o3 > 0.f ? o3 : __expf(o3) - 1.f;
        ushort4 h, l;
        h.x = f2bf(o0); l.x = f2bf(o0 - bf2f(h.x));
        h.y = f2bf(o1); l.y = f2bf(o1 - bf2f(h.y));
        h.z = f2bf(o2); l.z = f2bf(o2 - bf2f(h.z));
        h.w = f2bf(o3); l.w = f2bf(o3 - bf2f(h.w));
        *(ushort4*)(Hh + (size_t)n * 128 + 4 * j) = h;
        *(ushort4*)(Hl + (size_t)n * 128 + 4 * j) = l;
    }
}

// ---------------------------------------------------------------------------
// Aggregation layer 2: F=64, H=1. 8 edges per iteration (2 masked quad-passes,
// 2 gathers in flight). Quarter q = l>>4 selects edge; jj = l&15 owns
// channels 4jj..4jj+3. reduce16 = 4 DPP.
// ---------------------------------------------------------------------------
__global__ __launch_bounds__(256) void k_agg2(const float4* __restrict__ XL4,
                                              const float4* __restrict__ XR4,
                                              const float* __restrict__ att,
                                              const float* __restrict__ bias,
                                              const int* __restrict__ rowptr,
                                              const int* __restrict__ csrc,
                                              float* __restrict__ OUT) {
    const int lane = threadIdx.x & 63;
    const int wid = threadIdx.x >> 6;
    const int n = blockIdx.x * 4 + wid;
    if (n >= NN) return;
    const int beg = rowptr[n];
    const int end = rowptr[n + 1];
    const int q = lane >> 4;
    const int jj = lane & 15;

    const float4 xr = XR4[(size_t)n * 16 + jj];
    const float4 at = ((const float4*)att)[jj];
    float4 s = {0.f, 0.f, 0.f, 0.f};
    float d = 0.f;

    for (int i = beg; i < end; i += 8) {
        int i0 = i + q;
        int i1 = i + 4 + q;
        int e1 = end - 1;
        int s0 = csrc[min(i0, e1)];
        int s1 = csrc[min(i1, e1)];
        float4 v0 = XL4[(size_t)s0 * 16 + jj];
        float4 v1 = XL4[(size_t)s1 * 16 + jj];
        #pragma unroll
        for (int u = 0; u < 2; ++u) {
            float4 v = (u == 0) ? v0 : v1;
            int ii = (u == 0) ? i0 : i1;
            float t0 = lrelu(v.x + xr.x) * at.x;
            t0 = fmaf(lrelu(v.y + xr.y), at.y, t0);
            t0 = fmaf(lrelu(v.z + xr.z), at.z, t0);
            t0 = fmaf(lrelu(v.w + xr.w), at.w, t0);
            float p = expclamp(sum16(t0));
            if (ii >= end) p = 0.f;
            d += p;
            s.x = fmaf(p, v.x, s.x); s.y = fmaf(p, v.y, s.y);
            s.z = fmaf(p, v.z, s.z); s.w = fmaf(p, v.w, s.w);
        }
    }

    // combine the four quarters
    d   += __shfl_xor(d, 16);   d   += __shfl_xor(d, 32);
    s.x += __shfl_xor(s.x, 16); s.x += __shfl_xor(s.x, 32);
    s.y += __shfl_xor(s.y, 16); s.y += __shfl_xor(s.y, 32);
    s.z += __shfl_xor(s.z, 16); s.z += __shfl_xor(s.z, 32);
    s.w += __shfl_xor(s.w, 16); s.w += __shfl_xor(s.w, 32);

    if (lane < 16) {
        float inv = (d > 0.f) ? 1.f / d : 0.f;
        float4 bv = ((const float4*)bias)[jj];
        float4 o;
        o.x = fmaf(s.x, inv, bv.x);
        o.y = fmaf(s.y, inv, bv.y);
        o.z = fmaf(s.z, inv, bv.z);
        o.w = fmaf(s.w, inv, bv.w);
        *(float4*)(OUT + (size_t)n * 64 + 4 * jj) = o;
    }
}

// ---------------------------------------------------------------------------
extern "C" void kernel_launch(void* const* d_in, const int* in_sizes, int n_in,
                              void* d_out, int out_size, void* d_ws, size_t ws_size,
                              hipStream_t stream) {
    const float* x    = (const float*)d_in[0];
    const int*   ei   = (const int*)d_in[1];
    const int*   esrc = ei;
    const int*   edst = ei + EE;

    const float* Wl0 = (const float*)d_in[2];
    const float* bl0 = (const float*)d_in[3];
    const float* Wr0 = (const float*)d_in[4];
    const float* br0 = (const float*)d_in[5];
    const float* at0 = (const float*)d_in[6];
    const float* b0  = (const float*)d_in[7];
    const float* rs0 = (const float*)d_in[8];
    const float* Wl1 = (const float*)d_in[9];
    const float* bl1 = (const float*)d_in[10];
    const float* Wr1 = (const float*)d_in[11];
    const float* br1 = (const float*)d_in[12];
    const float* at1 = (const float*)d_in[13];
    const float* b1  = (const float*)d_in[14];
    const float* rs1 = (const float*)d_in[15];
    const float* Wl2 = (const float*)d_in[16];
    const float* bl2 = (const float*)d_in[17];
    const float* Wr2 = (const float*)d_in[18];
    const float* br2 = (const float*)d_in[19];
    const float* at2 = (const float*)d_in[20];
    const float* b2  = (const float*)d_in[21];

    float* out = (float*)d_out;

    // --- workspace layout ---
    float* XL  = (float*)d_ws;                 // [NN*128] fp32 row-major
    float* XR  = XL + (size_t)NN * 128;
    float* RES = XR + (size_t)NN * 128;
    ushort* Xh = (ushort*)(RES + (size_t)NN * 128);   // [NN*128] bf16-hi (H)
    ushort* Xl_ = Xh + (size_t)NN * 128;              // [NN*128] bf16-lo (H)
    ushort* Wth = Xl_ + (size_t)NN * 128;
    const int wsz[8] = {16384, 16384, 16384, 16384, 16384, 16384, 8192, 8192};
    ushort* th[8]; ushort* tl[8];
    {
        ushort* p = Wth;
        for (int i = 0; i < 8; ++i) { th[i] = p; p += wsz[i]; }
        for (int i = 0; i < 8; ++i) { tl[i] = p; p += wsz[i]; }
    }
    int* deg    = (int*)(Wth + 2 * (6 * 16384 + 2 * 8192));
    int* rowptr = deg + NN;                    // NN+1
    int* cursor = rowptr + (NN + 1);
    int* csrc   = cursor + NN;                 // EE
    int* bsum   = csrc + EE;                   // NB
    int* boff   = bsum + NB;                   // NB

    // --- CSR build (graph identical across layers) ---
    hipMemsetAsync(deg, 0, NN * sizeof(int), stream);
    k_hist<<<(EE + 255) / 256, 256, 0, stream>>>(edst, deg);
    k_scan1<<<NB, 256, 0, stream>>>(deg, bsum);
    k_scan2<<<1, 256, 0, stream>>>(bsum, boff);
    k_scan3<<<NB, 256, 0, stream>>>(deg, boff, rowptr, cursor);
    k_scatter<<<(EE + 255) / 256, 256, 0, stream>>>(esrc, edst, cursor, csrc);

    // --- weight conversion ---
    WPack wp;
    const float* Ws[8] = {Wl0, Wr0, rs0, Wl1, Wr1, rs1, Wl2, Wr2};
    const int fouts[8] = {128, 128, 128, 128, 128, 128, 64, 64};
    for (int i = 0; i < 8; ++i) { wp.W[i] = Ws[i]; wp.Th[i] = th[i]; wp.Tl[i] = tl[i]; wp.fout[i] = fouts[i]; }
    k_conv_w<<<dim3(64, 8), 256, 0, stream>>>(wp);

    const int gemm_grid = (NN + 127) / 128;
    const int agg_grid  = (NN + 3) / 4;

    // --- Layer 0 (A from fp32 x, split on the fly) ---
    k_gemm_mfma<128, 3, true><<<gemm_grid, 256, 0, stream>>>(x, nullptr, nullptr,
        th[0], tl[0], bl0, th[1], tl[1], br0, th[2], tl[2], XL, XR, RES);
    k_agg01<<<agg_grid, 256, 0, stream>>>((const float4*)XL, (const float4*)XR, (const float4*)RES,
        at0, b0, rowptr, csrc, Xh, Xl_);

    // --- Layer 1 ---
    k_gemm_mfma<128, 3, false><<<gemm_grid, 256, 0, stream>>>(nullptr, Xh, Xl_,
        th[3], tl[3], bl1, th[4], tl[4], br1, th[5], tl[5], XL, XR, RES);
    k_agg01<<<agg_grid, 256, 0, stream>>>((const float4*)XL, (const float4*)XR, (const float4*)RES,
        at1, b1, rowptr, csrc, Xh, Xl_);

    // --- Layer 2 (heads=1, C=64, no residual, no ELU) ---
    k_gemm_mfma<64, 2, false><<<gemm_grid, 256, 0, stream>>>(nullptr, Xh, Xl_,
        th[6], tl[6], bl2, th[7], tl[7], br2, nullptr, nullptr, XL, XR, nullptr);
    k_agg2<<<agg_grid, 256, 0, stream>>>((const float4*)XL, (const float4*)XR, at2, b2, rowptr, csrc, out);
}